// Round 6
// baseline (537.055 us; speedup 1.0000x reference)
//
#include <hip/hip_runtime.h>
#include <hip/hip_bf16.h>
#include <math.h>

#define N_NODES 100000
#define N_EDGES 1600000
#define N_FEAT 75
#define HID 64
#define NUM_GRAPHS 4096
#define BN_EPS 1e-5f
#define NSLICE 16

#define NBIN 400          // bins of 250 nodes
#define NPB 250
#define BCAP 4800         // staging capacity per bin
#define CSRCAP 6552       // padded csr capacity per bin (multiple of 8)
#define BIN_BLOCKS 256
#define BIN_CHUNK ((N_EDGES + BIN_BLOCKS - 1) / BIN_BLOCKS)   // 6250

#define NGRP 6250         // 16-position MFMA groups (6250*16 == N_NODES)
#define TW   4096         // scheduled waves for the fused gather (16/CU sustained)

#define XPAD 68           // LDS row stride (words): 16B-aligned, bank-shift 4

typedef short bf16x8 __attribute__((ext_vector_type(8)));
typedef float f32x4 __attribute__((ext_vector_type(4)));

// ---------------- bf16 helpers ----------------

__device__ __forceinline__ unsigned bf2_pack(float a, float b) {
  unsigned ua = __float_as_uint(a); ua += 0x7FFF + ((ua >> 16) & 1);
  unsigned ub = __float_as_uint(b); ub += 0x7FFF + ((ub >> 16) & 1);
  return (ua >> 16) | (ub & 0xFFFF0000u);
}
__device__ __forceinline__ unsigned short bf1_pack(float a) {
  unsigned ua = __float_as_uint(a); ua += 0x7FFF + ((ua >> 16) & 1);
  return (unsigned short)(ua >> 16);
}
__device__ __forceinline__ float bf1_unpack(unsigned short u) {
  return __uint_as_float((unsigned)u << 16);
}
// accumulate 8 bf16 (one uint4) into 8 f32 lane-local regs
__device__ __forceinline__ void acc8(float* a, uint4 u) {
  a[0] += __uint_as_float(u.x << 16);
  a[1] += __uint_as_float(u.x & 0xFFFF0000u);
  a[2] += __uint_as_float(u.y << 16);
  a[3] += __uint_as_float(u.y & 0xFFFF0000u);
  a[4] += __uint_as_float(u.z << 16);
  a[5] += __uint_as_float(u.z & 0xFFFF0000u);
  a[6] += __uint_as_float(u.w << 16);
  a[7] += __uint_as_float(u.w & 0xFFFF0000u);
}

// ---------------- setup: LDS-binned counting sort into PADDED, DEGREE-SORTED csr ------

__global__ __launch_bounds__(256) void bin_kernel(const int* __restrict__ src,
                                                  const int* __restrict__ dst,
                                                  int* __restrict__ binCur,
                                                  unsigned* __restrict__ staging,
                                                  unsigned short* __restrict__ WswId) {
  __shared__ unsigned ent[BIN_CHUNK];
  __shared__ short binv[BIN_CHUNK];
  __shared__ int lcnt[NBIN];
  __shared__ int lbase[NBIN];
  int t = threadIdx.x;
  if (blockIdx.x == 0) {
    // identity W in the MFMA-swizzled layout (for the layer-1 fused pass)
    for (int i = t; i < HID * HID; i += 256) {
      int j = i & 7, lane2 = (i >> 3) & 63, rest = i >> 9;
      int kc = rest & 1, nt = rest >> 1;
      int k = kc * 32 + ((lane2 >> 4) & 3) * 8 + j;
      int nn = nt * 16 + (lane2 & 15);
      WswId[i] = (k == nn) ? (unsigned short)0x3F80 : (unsigned short)0;
    }
  }
  int c0 = blockIdx.x * BIN_CHUNK;
  int c1 = min(c0 + BIN_CHUNK, N_EDGES);
  int n = c1 - c0;
  for (int i = t; i < NBIN; i += 256) lcnt[i] = 0;
  __syncthreads();
  for (int i = t; i < n; i += 256) {
    int d = dst[c0 + i];
    int s = src[c0 + i];
    int b = d / NPB;
    int ld = d - b * NPB;
    ent[i] = ((unsigned)ld << 17) | (unsigned)s;
    binv[i] = (short)b;
    atomicAdd(&lcnt[b], 1);
  }
  __syncthreads();
  for (int i = t; i < NBIN; i += 256)
    lbase[i] = atomicAdd(&binCur[i], lcnt[i]);
  __syncthreads();
  for (int i = t; i < n; i += 256) {
    int b = binv[i];
    int slot = atomicAdd(&lbase[b], 1);
    if (slot < BCAP) staging[(size_t)b * BCAP + slot] = ent[i];
  }
}

__global__ __launch_bounds__(256) void sort_kernel(const unsigned* __restrict__ staging,
                                                   const int* __restrict__ binCur,
                                                   float* __restrict__ dinv,
                                                   int2* __restrict__ rowSE,
                                                   int* __restrict__ perm,
                                                   int* __restrict__ csr) {
  __shared__ unsigned in[BCAP];
  __shared__ int outw[CSRCAP];
  __shared__ int cnt[NPB];
  __shared__ int hist[64];
  __shared__ int histCur[64];
  __shared__ int rnk[NPB];
  __shared__ int pd[256];
  __shared__ int ptot;
  int b = blockIdx.x, t = threadIdx.x;
  int n = min(binCur[b], BCAP);
  const unsigned* st = staging + (size_t)b * BCAP;
  for (int i = t; i < NPB; i += 256) cnt[i] = 0;
  if (t < 64) hist[t] = 0;
  __syncthreads();
  for (int i = t; i < n; i += 256) {
    unsigned e = st[i];
    in[i] = e;
    atomicAdd(&cnt[e >> 17], 1);
  }
  __syncthreads();
  int deg = (t < NPB) ? cnt[t] : 0;
  int db = min(deg, 63);
  if (t < NPB) atomicAdd(&hist[db], 1);
  __syncthreads();
  if (t < 64) {                       // exclusive scan of 64-bucket degree histogram
    int h = hist[t];
    int x = h;
    #pragma unroll
    for (int off = 1; off < 64; off <<= 1) {
      int y = __shfl_up(x, off);
      if (t >= off) x += y;
    }
    histCur[t] = x - h;
  }
  __syncthreads();
  int rank = 0;
  if (t < NPB) {
    rank = atomicAdd(&histCur[db], 1);  // unique rank, degree-ascending
    rnk[t] = rank;
  }
  pd[t] = 0;
  __syncthreads();
  int pdeg = (deg + 7) & ~7;
  if (t < NPB) pd[rank] = pdeg;
  __syncthreads();
  for (int off = 1; off < 256; off <<= 1) {   // inclusive scan of padded degrees (rank order)
    int a = (t >= off) ? pd[t - off] : 0;
    __syncthreads();
    pd[t] += a;
    __syncthreads();
  }
  if (t == 255) ptot = pd[255];
  __syncthreads();
  int base = b * CSRCAP;
  if (t < NPB) {
    int r = rnk[t];
    int excl = pd[r] - pdeg;
    int v = b * NPB + t;
    int pos = b * NPB + r;
    dinv[v] = rsqrtf((float)deg + 1.0f);
    rowSE[pos] = make_int2(base + excl, base + excl + pdeg);
    perm[pos] = v;
    cnt[t] = excl;                    // scatter cursor (node-local id)
  }
  if (b == 0 && t == 0) dinv[N_NODES] = 0.f;   // sentinel
  __syncthreads();
  int ptotal = min(ptot, CSRCAP);
  for (int i = t; i < ptotal; i += 256) outw[i] = N_NODES;   // sentinel fill
  __syncthreads();
  for (int i = t; i < n; i += 256) {
    unsigned e = in[i];
    int p = atomicAdd(&cnt[e >> 17], 1);
    if (p < CSRCAP) outw[p] = (int)(e & 0x1FFFFu);
  }
  __syncthreads();
  for (int i = t; i < ptotal; i += 256) csr[base + i] = outw[i];
}

// ---------------- edge-balanced wave schedule -----------------------------------------
// Partitions the 100000 degree-sorted positions into TW contiguous ranges of ≈equal
// total weight (pdeg+2 per position). Waves keep consecutive ranks (lockstep-uniform
// degrees); boundary MFMA groups are shared by two waves with row masking.

__global__ __launch_bounds__(256) void sched_kernel(const int2* __restrict__ rowSE,
                                                    int2* __restrict__ sched) {
  __shared__ int incl[NGRP];
  __shared__ int wsum[4];
  __shared__ int carry;
  __shared__ int pstart[TW + 1];
  int t = threadIdx.x;
  for (int g = t; g < NGRP; g += 256) {
    int s = 0;
    int basep = g * 16;
    #pragma unroll
    for (int j = 0; j < 16; ++j) {
      int2 se = rowSE[basep + j];
      s += (se.y - se.x) + 2;
    }
    incl[g] = s;
  }
  if (t == 0) carry = 0;
  __syncthreads();
  int lane = t & 63, wv = t >> 6;
  int nch = (NGRP + 255) / 256;
  for (int c = 0; c < nch; ++c) {
    int idx = c * 256 + t;
    int v = (idx < NGRP) ? incl[idx] : 0;
    int x = v;
    #pragma unroll
    for (int off = 1; off < 64; off <<= 1) {
      int y = __shfl_up(x, off);
      if (lane >= off) x += y;
    }
    if (lane == 63) wsum[wv] = x;
    __syncthreads();
    int add = carry;
    for (int i = 0; i < wv; ++i) add += wsum[i];
    x += add;
    if (idx < NGRP) incl[idx] = x;
    __syncthreads();
    if (t == 255) carry = x;
    __syncthreads();
  }
  int total = incl[NGRP - 1];
  int Q = (total + TW - 1) / TW;
  for (int w2 = t; w2 <= TW; w2 += 256) {
    int X = w2 * Q;   // total+TW fits int
    int p;
    if (X <= 0) p = 0;
    else if (X > total) p = N_NODES;
    else {
      int lo = 0, hi = NGRP;
      while (lo < hi) { int m = (lo + hi) >> 1; if (incl[m] >= X) hi = m; else lo = m + 1; }
      if (lo >= NGRP) p = N_NODES;
      else {
        int basev = lo ? incl[lo - 1] : 0;
        int pp = lo * 16;
        p = pp + 16;
        for (int j = 0; j < 16; ++j) {
          int2 se = rowSE[pp + j];
          basev += (se.y - se.x) + 2;
          if (basev >= X) { p = pp + j + 1; break; }
        }
      }
    }
    pstart[w2] = min(p, N_NODES);
  }
  __syncthreads();
  for (int w2 = t; w2 < TW; w2 += 256)
    sched[w2] = make_int2(pstart[w2], pstart[w2 + 1]);
}

// ---------------- GEMM layer 1: fp32 X [N,75] @ W -> bf16 Hs (VALU) ----------------

__global__ __launch_bounds__(256) void gemm1_kernel(
    const float* __restrict__ X, const float* __restrict__ W,
    const float* __restrict__ dinv, unsigned short* __restrict__ Hout) {
  __shared__ float xs[N_FEAT][XPAD];   // [k][row]
  __shared__ float ws[N_FEAT][64];     // [k][col]
  int t = threadIdx.x;
  int rowBase = blockIdx.x * 64;
  for (int i = t; i < N_FEAT * 64; i += 256) ws[i >> 6][i & 63] = W[i];
  if (rowBase + 64 <= N_NODES) {
    const float* Xb = X + (size_t)rowBase * N_FEAT;
    for (int i = t; i < 64 * N_FEAT; i += 256) {
      int r = i / N_FEAT, k = i - r * N_FEAT;
      xs[k][r] = Xb[i];
    }
  } else {
    for (int i = t; i < 64 * N_FEAT; i += 256) {
      int r = i / N_FEAT, k = i - r * N_FEAT;
      int row = rowBase + r;
      xs[k][r] = (row < N_NODES) ? X[(size_t)row * N_FEAT + k] : 0.f;
    }
  }
  __syncthreads();
  int ty = t >> 4, tx = t & 15;
  int r0 = ty * 4, c0 = tx * 4;
  float acc[4][4] = {};
  for (int k = 0; k < N_FEAT; ++k) {
    float4 a = *(const float4*)&xs[k][r0];
    float4 bq = *(const float4*)&ws[k][c0];
    float av[4] = {a.x, a.y, a.z, a.w};
    float bv[4] = {bq.x, bq.y, bq.z, bq.w};
    #pragma unroll
    for (int i = 0; i < 4; ++i)
      #pragma unroll
      for (int j = 0; j < 4; ++j)
        acc[i][j] = fmaf(av[i], bv[j], acc[i][j]);
  }
  #pragma unroll
  for (int i = 0; i < 4; ++i) {
    int row = rowBase + r0 + i;
    if (row < N_NODES) {
      float dv = dinv[row];
      uint2 packed = make_uint2(bf2_pack(acc[i][0] * dv, acc[i][1] * dv),
                                bf2_pack(acc[i][2] * dv, acc[i][3] * dv));
      *(uint2*)&Hout[(size_t)row * HID + c0] = packed;
    } else if (row == N_NODES) {
      *(uint2*)&Hout[(size_t)row * HID + c0] = make_uint2(0u, 0u);
    }
  }
}

// ---------------- layers 1-4 FUSED: gather(Z) -> MFMA(Wsw) -> relu/BN-stats -> Z ------
// One wave per block; each wave walks its edge-balanced position range (sched) over
// 16-position MFMA groups. Boundary groups are processed by both adjacent waves with
// row masking (C rows are independent, masked rows have zero A fragments).
// Layer 1: swizzled IDENTITY W (MFMA = transpose) + computeS (folds ssum).

__global__ __launch_bounds__(64) void fusedB_kernel(
    const unsigned short* __restrict__ Zin, const unsigned short* __restrict__ Wsw,
    const int* __restrict__ csr, const int2* __restrict__ rowSE,
    const int* __restrict__ perm, float* __restrict__ Ssum,
    const float* __restrict__ dinv, const float* __restrict__ cvec,
    const float* __restrict__ bias, unsigned short* __restrict__ Zout,
    float* __restrict__ stats, const int2* __restrict__ sched,
    int scaleOut, int computeS) {
  __shared__ float ldsC[16][68];
  int t = threadIdx.x;
  int q = t >> 4, li = t & 15;
  if (blockIdx.x == 0 && t < 8)   // zero sentinel row of the OUTPUT buffer
    ((uint4*)(Zout + (size_t)N_NODES * HID))[t] = make_uint4(0u, 0u, 0u, 0u);
  int2 rng = sched[blockIdx.x];
  float ss[4] = {0.f, 0.f, 0.f, 0.f}, sq[4] = {0.f, 0.f, 0.f, 0.f};
  const bf16x8* Wr = (const bf16x8*)Wsw;
  const unsigned short* Zq = Zin + q * 8;
  if (rng.x < rng.y) {
    int gS = rng.x >> 4, gE = (rng.y - 1) >> 4;
    for (int g = gS; g <= gE; ++g) {
      int pos = g * 16 + li;
      bool act = (pos >= rng.x) && (pos < rng.y);
      float aLo[8] = {0.f, 0.f, 0.f, 0.f, 0.f, 0.f, 0.f, 0.f};
      float aHi[8] = {0.f, 0.f, 0.f, 0.f, 0.f, 0.f, 0.f, 0.f};
      if (act) {
        int v = perm[pos];
        int2 se = rowSE[pos];
        const unsigned short* rs = Zq + (size_t)v * HID;
        acc8(aLo, *(const uint4*)rs);
        acc8(aHi, *(const uint4*)(rs + 32));
        if (computeS) {
          float sdv = 0.f;
          for (int e = se.x; e < se.y; e += 4) {
            int4 cc = *(const int4*)&csr[e];
            const unsigned short* r0 = Zq + (size_t)cc.x * HID;
            const unsigned short* r1 = Zq + (size_t)cc.y * HID;
            const unsigned short* r2 = Zq + (size_t)cc.z * HID;
            const unsigned short* r3 = Zq + (size_t)cc.w * HID;
            uint4 l0 = *(const uint4*)r0, h0 = *(const uint4*)(r0 + 32);
            uint4 l1 = *(const uint4*)r1, h1 = *(const uint4*)(r1 + 32);
            uint4 l2 = *(const uint4*)r2, h2 = *(const uint4*)(r2 + 32);
            uint4 l3 = *(const uint4*)r3, h3 = *(const uint4*)(r3 + 32);
            sdv += (dinv[cc.x] + dinv[cc.y]) + (dinv[cc.z] + dinv[cc.w]);
            acc8(aLo, l0); acc8(aHi, h0);
            acc8(aLo, l1); acc8(aHi, h1);
            acc8(aLo, l2); acc8(aHi, h2);
            acc8(aLo, l3); acc8(aHi, h3);
          }
          if (q == 0) {
            float dvv = dinv[v];
            Ssum[v] = dvv * (dvv + sdv);
          }
        } else {
          for (int e = se.x; e < se.y; e += 4) {
            int4 cc = *(const int4*)&csr[e];
            const unsigned short* r0 = Zq + (size_t)cc.x * HID;
            const unsigned short* r1 = Zq + (size_t)cc.y * HID;
            const unsigned short* r2 = Zq + (size_t)cc.z * HID;
            const unsigned short* r3 = Zq + (size_t)cc.w * HID;
            uint4 l0 = *(const uint4*)r0, h0 = *(const uint4*)(r0 + 32);
            uint4 l1 = *(const uint4*)r1, h1 = *(const uint4*)(r1 + 32);
            uint4 l2 = *(const uint4*)r2, h2 = *(const uint4*)(r2 + 32);
            uint4 l3 = *(const uint4*)r3, h3 = *(const uint4*)(r3 + 32);
            acc8(aLo, l0); acc8(aHi, h0);
            acc8(aLo, l1); acc8(aHi, h1);
            acc8(aLo, l2); acc8(aHi, h2);
            acc8(aLo, l3); acc8(aHi, h3);
          }
        }
      }
      // ---- pack A-frags + MFMA (masked rows are zero) ----
      bf16x8 a0, a1;
      #pragma unroll
      for (int j = 0; j < 8; ++j) {
        a0[j] = (short)bf1_pack(aLo[j]);
        a1[j] = (short)bf1_pack(aHi[j]);
      }
      f32x4 accs[4];
      #pragma unroll
      for (int nt = 0; nt < 4; ++nt) {
        bf16x8 b0 = Wr[(nt * 2 + 0) * 64 + t];
        bf16x8 b1 = Wr[(nt * 2 + 1) * 64 + t];
        f32x4 acc = {0.f, 0.f, 0.f, 0.f};
        acc = __builtin_amdgcn_mfma_f32_16x16x32_bf16(a0, b0, acc, 0, 0, 0);
        acc = __builtin_amdgcn_mfma_f32_16x16x32_bf16(a1, b1, acc, 0, 0, 0);
        accs[nt] = acc;
      }
      // ---- epilogue: C row = q*4+r, col = nt*16+li ----
      float dvr[4], svr[4], str[4];
      bool actR[4];
      #pragma unroll
      for (int r = 0; r < 4; ++r) {
        int pr2 = g * 16 + q * 4 + r;
        actR[r] = (pr2 >= rng.x) && (pr2 < rng.y);
        if (actR[r]) {
          int vr = perm[pr2];
          dvr[r] = dinv[vr];
          svr[r] = computeS ? 0.f : Ssum[vr];   // layer 1: cvec==0, S unused
        } else { dvr[r] = 0.f; svr[r] = 0.f; }
        str[r] = scaleOut ? dvr[r] : 1.f;
      }
      #pragma unroll
      for (int nt = 0; nt < 4; ++nt) {
        float cl = cvec[nt * 16 + li];
        float bl = bias[nt * 16 + li];
        #pragma unroll
        for (int r = 0; r < 4; ++r) {
          float z = fmaxf(fmaf(dvr[r], accs[nt][r], fmaf(svr[r], cl, bl)), 0.f);
          if (!actR[r]) z = 0.f;
          ss[nt] += z;
          sq[nt] += z * z;
          ldsC[q * 4 + r][nt * 16 + li] = z * str[r];
        }
      }
      __syncthreads();
      // ---- transpose out: 4 threads/row, 32B each ----
      int rl = t >> 2, cq = t & 3;
      int pr3 = g * 16 + rl;
      if (pr3 >= rng.x && pr3 < rng.y) {
        int v2 = perm[pr3];
        unsigned p[8];
        #pragma unroll
        for (int j = 0; j < 8; ++j)
          p[j] = bf2_pack(ldsC[rl][cq * 16 + 2 * j], ldsC[rl][cq * 16 + 2 * j + 1]);
        uint4* dp = (uint4*)(Zout + (size_t)v2 * HID + cq * 16);
        dp[0] = make_uint4(p[0], p[1], p[2], p[3]);
        dp[1] = make_uint4(p[4], p[5], p[6], p[7]);
      }
      __syncthreads();
    }
  }
  // ---- stats: reduce across q (lane bits 4,5), one atomic set per wave ----
  #pragma unroll
  for (int m = 16; m <= 32; m <<= 1) {
    #pragma unroll
    for (int nt = 0; nt < 4; ++nt) {
      ss[nt] += __shfl_xor(ss[nt], m);
      sq[nt] += __shfl_xor(sq[nt], m);
    }
  }
  if (q == 0) {
    float* slp = stats + (size_t)(blockIdx.x & (NSLICE - 1)) * 128;
    #pragma unroll
    for (int nt = 0; nt < 4; ++nt) {
      atomicAdd(&slp[nt * 16 + li], ss[nt]);
      atomicAdd(&slp[64 + nt * 16 + li], sq[nt]);
    }
  }
}

// ---------------- BN fold: alpha/beta, Wsw = swizzled bf16(alpha⊙W), c = beta@W -------

__global__ __launch_bounds__(256) void prep_kernel(
    const float* __restrict__ stats, const float* __restrict__ g,
    const float* __restrict__ be, const float* __restrict__ Wnext,
    unsigned short* __restrict__ Wsw, float* __restrict__ cvec,
    float* __restrict__ ab, int hasNext) {
  __shared__ float tmp2[256];
  __shared__ float alpha[64];
  __shared__ float beta[64];
  __shared__ float cpart[4][64];
  int t = threadIdx.x;
  {
    int elem = t & 127, half = t >> 7;
    float s = 0.f;
    #pragma unroll
    for (int i = 0; i < NSLICE / 2; ++i)
      s += stats[(size_t)(half * (NSLICE / 2) + i) * 128 + elem];
    tmp2[t] = s;
  }
  __syncthreads();
  if (t < 64) {
    float sm = tmp2[t] + tmp2[t + 128];
    float sq = tmp2[64 + t] + tmp2[192 + t];
    float m = sm / (float)N_NODES;
    float var = sq / (float)N_NODES - m * m;
    float a = g[t] * rsqrtf(var + BN_EPS);
    alpha[t] = a;
    float bt = be[t] - m * a;
    beta[t] = bt;
    ab[t] = a;
    ab[64 + t] = bt;
  }
  __syncthreads();
  if (hasNext) {
    for (int idx = t; idx < HID * HID; idx += 256) {
      int j = idx & 7, lane2 = (idx >> 3) & 63, rest = idx >> 9;
      int kc = rest & 1, nt = rest >> 1;
      int k = kc * 32 + ((lane2 >> 4) & 3) * 8 + j;
      int nn = nt * 16 + (lane2 & 15);
      Wsw[idx] = bf1_pack(alpha[k] * Wnext[k * HID + nn]);
    }
    {
      int col = t & 63, kseg = t >> 6;
      float c = 0.f;
      #pragma unroll
      for (int i = 0; i < 16; ++i) {
        int k = kseg * 16 + i;
        c += beta[k] * Wnext[k * HID + col];
      }
      cpart[kseg][col] = c;
    }
    __syncthreads();
    if (t < 64)
      cvec[t] = (cpart[0][t] + cpart[1][t]) + (cpart[2][t] + cpart[3][t]);
  }
}

// ---------------- pool (bf16 Z, unscaled layer-4 output) ----------------

#define POOL_CH 64

__global__ __launch_bounds__(256) void pool_kernel(
    const unsigned short* __restrict__ Z, const int* __restrict__ batch,
    const float* __restrict__ ab, float* __restrict__ out) {
  int tid = blockIdx.x * blockDim.x + threadIdx.x;
  int w = tid >> 6, lane = tid & 63;
  int v0 = w * POOL_CH;
  if (v0 >= N_NODES) return;
  int v1 = min(N_NODES, v0 + POOL_CH);
  float a = ab[lane], b = ab[64 + lane];
  float acc = 0.f;
  int cur = batch[v0];
  for (int v = v0; v < v1; ++v) {
    int bg = batch[v];
    if (bg != cur) {
      atomicAdd(&out[(size_t)cur * HID + lane], acc);
      acc = 0.f;
      cur = bg;
    }
    acc = fmaf(bf1_unpack(Z[(size_t)v * HID + lane]), a, acc + b);
  }
  atomicAdd(&out[(size_t)cur * HID + lane], acc);
}

// ---------------- launch ----------------

extern "C" void kernel_launch(void* const* d_in, const int* in_sizes, int n_in,
                              void* d_out, int out_size, void* d_ws, size_t ws_size,
                              hipStream_t stream) {
  const float* x    = (const float*)d_in[0];
  const int* src    = (const int*)d_in[1];
  const int* dst    = (const int*)d_in[2];
  const int* batch  = (const int*)d_in[3];
  const float* W[4]  = {(const float*)d_in[4], (const float*)d_in[8],
                        (const float*)d_in[12], (const float*)d_in[16]};
  const float* b[4]  = {(const float*)d_in[5], (const float*)d_in[9],
                        (const float*)d_in[13], (const float*)d_in[17]};
  const float* g[4]  = {(const float*)d_in[6], (const float*)d_in[10],
                        (const float*)d_in[14], (const float*)d_in[18]};
  const float* be[4] = {(const float*)d_in[7], (const float*)d_in[11],
                        (const float*)d_in[15], (const float*)d_in[19]};

  char* wsb = (char*)d_ws;
  size_t off = 0;
  auto alloc = [&](size_t bytes) -> void* {
    void* p = wsb + off;
    off += (bytes + 255) & ~(size_t)255;
    return p;
  };
  // zeroed region (one memset)
  int*   binCur = (int*)  alloc((size_t)NBIN * 4);
  float* c0     = (float*)alloc(64 * 4);
  float* stats  = (float*)alloc((size_t)4 * NSLICE * 128 * 4);
  size_t zero_bytes = off;
  // non-zeroed
  float* Ssum   = (float*)alloc((size_t)N_NODES * 4);
  int2*  rowSE  = (int2*) alloc((size_t)N_NODES * 8);
  int*   perm   = (int*)  alloc((size_t)N_NODES * 4);
  float* dinv   = (float*)alloc((size_t)(N_NODES + 1) * 4);
  int2*  sched  = (int2*) alloc((size_t)TW * 8);
  unsigned* staging = (unsigned*)alloc((size_t)NBIN * BCAP * 4);
  int*   csr    = (int*)  alloc((size_t)NBIN * CSRCAP * 4);
  unsigned short* Hb  = (unsigned short*)alloc((size_t)(N_NODES + 1) * HID * 2);
  unsigned short* Z0  = (unsigned short*)alloc((size_t)(N_NODES + 1) * HID * 2);
  unsigned short* Z1  = (unsigned short*)alloc((size_t)(N_NODES + 1) * HID * 2);
  unsigned short* Wsw = (unsigned short*)alloc((size_t)HID * HID * 2);
  unsigned short* WswId = (unsigned short*)alloc((size_t)HID * HID * 2);
  float* cv     = (float*)alloc(64 * 4);
  float* ab     = (float*)alloc(128 * 4);

  hipMemsetAsync(d_ws, 0, zero_bytes, stream);
  hipMemsetAsync(d_out, 0, (size_t)out_size * 4, stream);

  bin_kernel<<<BIN_BLOCKS, 256, 0, stream>>>(src, dst, binCur, staging, WswId);
  sort_kernel<<<NBIN, 256, 0, stream>>>(staging, binCur, dinv, rowSE, perm, csr);
  sched_kernel<<<1, 256, 0, stream>>>(rowSE, sched);

  int gemmBlocks = (N_NODES + 64) / 64;   // covers sentinel row N_NODES

  // layer 1 (K=75, c=0): gemm1 -> fused gather with identity W (MFMA = transpose),
  // computeS=1 folds the former ssum_kernel into the gather.
  gemm1_kernel<<<gemmBlocks, 256, 0, stream>>>(x, W[0], dinv, Hb);
  fusedB_kernel<<<TW, 64, 0, stream>>>(Hb, WswId, csr, rowSE, perm, Ssum, dinv,
                                       c0, b[0], Z0, stats, sched, 1, 1);
  prep_kernel<<<1, 256, 0, stream>>>(stats, g[0], be[0], W[1], Wsw, cv, ab, 1);

  // layers 2..4: fused gather+MFMA+BN-stats, ping-pong Z buffers
  fusedB_kernel<<<TW, 64, 0, stream>>>(Z0, Wsw, csr, rowSE, perm, Ssum, dinv,
                                       cv, b[1], Z1, stats + (size_t)1 * NSLICE * 128,
                                       sched, 1, 0);
  prep_kernel<<<1, 256, 0, stream>>>(stats + (size_t)1 * NSLICE * 128, g[1], be[1],
                                     W[2], Wsw, cv, ab, 1);
  fusedB_kernel<<<TW, 64, 0, stream>>>(Z1, Wsw, csr, rowSE, perm, Ssum, dinv,
                                       cv, b[2], Z0, stats + (size_t)2 * NSLICE * 128,
                                       sched, 1, 0);
  prep_kernel<<<1, 256, 0, stream>>>(stats + (size_t)2 * NSLICE * 128, g[2], be[2],
                                     W[3], Wsw, cv, ab, 1);
  fusedB_kernel<<<TW, 64, 0, stream>>>(Z0, Wsw, csr, rowSE, perm, Ssum, dinv,
                                       cv, b[3], Z1, stats + (size_t)3 * NSLICE * 128,
                                       sched, 0, 0);
  prep_kernel<<<1, 256, 0, stream>>>(stats + (size_t)3 * NSLICE * 128, g[3], be[3],
                                     nullptr, Wsw, cv, ab, 0);

  int poolBlocks = (N_NODES + 4 * POOL_CH - 1) / (4 * POOL_CH);
  pool_kernel<<<poolBlocks, 256, 0, stream>>>(Z1, batch, ab, (float*)d_out);
}

// Round 7
// 392.074 us; speedup vs baseline: 1.3698x; 1.3698x over previous
//
#include <hip/hip_runtime.h>
#include <hip/hip_bf16.h>
#include <math.h>

#define N_NODES 100000
#define N_EDGES 1600000
#define N_FEAT 75
#define HID 64
#define NUM_GRAPHS 4096
#define BN_EPS 1e-5f
#define NSLICE 16

#define NBIN 400          // bins of 250 nodes
#define NPB 250
#define BCAP 4800         // staging capacity per bin
#define CSRCAP 6552       // padded csr capacity per bin (multiple of 8)
#define BIN_BLOCKS 256
#define BIN_CHUNK ((N_EDGES + BIN_BLOCKS - 1) / BIN_BLOCKS)   // 6250

#define XPAD 68           // LDS row stride (words): 16B-aligned, bank-shift 4

typedef short bf16x8 __attribute__((ext_vector_type(8)));
typedef float f32x4 __attribute__((ext_vector_type(4)));

// ---------------- bf16 helpers ----------------

__device__ __forceinline__ unsigned bf2_pack(float a, float b) {
  unsigned ua = __float_as_uint(a); ua += 0x7FFF + ((ua >> 16) & 1);
  unsigned ub = __float_as_uint(b); ub += 0x7FFF + ((ub >> 16) & 1);
  return (ua >> 16) | (ub & 0xFFFF0000u);
}
__device__ __forceinline__ unsigned short bf1_pack(float a) {
  unsigned ua = __float_as_uint(a); ua += 0x7FFF + ((ua >> 16) & 1);
  return (unsigned short)(ua >> 16);
}
__device__ __forceinline__ float bf1_unpack(unsigned short u) {
  return __uint_as_float((unsigned)u << 16);
}
// accumulate 8 bf16 (one uint4) into 8 f32 lane-local regs
__device__ __forceinline__ void acc8(float* a, uint4 u) {
  a[0] += __uint_as_float(u.x << 16);
  a[1] += __uint_as_float(u.x & 0xFFFF0000u);
  a[2] += __uint_as_float(u.y << 16);
  a[3] += __uint_as_float(u.y & 0xFFFF0000u);
  a[4] += __uint_as_float(u.z << 16);
  a[5] += __uint_as_float(u.z & 0xFFFF0000u);
  a[6] += __uint_as_float(u.w << 16);
  a[7] += __uint_as_float(u.w & 0xFFFF0000u);
}

// ---------------- setup: LDS-binned counting sort into PADDED, DEGREE-SORTED csr ------

__global__ __launch_bounds__(256) void bin_kernel(const int* __restrict__ src,
                                                  const int* __restrict__ dst,
                                                  int* __restrict__ binCur,
                                                  unsigned* __restrict__ staging,
                                                  unsigned short* __restrict__ WswId) {
  __shared__ unsigned ent[BIN_CHUNK];
  __shared__ short binv[BIN_CHUNK];
  __shared__ int lcnt[NBIN];
  __shared__ int lbase[NBIN];
  int t = threadIdx.x;
  if (blockIdx.x == 0) {
    // identity W in the MFMA-swizzled layout (for the layer-1 fused pass)
    for (int i = t; i < HID * HID; i += 256) {
      int j = i & 7, lane2 = (i >> 3) & 63, rest = i >> 9;
      int kc = rest & 1, nt = rest >> 1;
      int k = kc * 32 + ((lane2 >> 4) & 3) * 8 + j;
      int nn = nt * 16 + (lane2 & 15);
      WswId[i] = (k == nn) ? (unsigned short)0x3F80 : (unsigned short)0;
    }
  }
  int c0 = blockIdx.x * BIN_CHUNK;
  int c1 = min(c0 + BIN_CHUNK, N_EDGES);
  int n = c1 - c0;
  for (int i = t; i < NBIN; i += 256) lcnt[i] = 0;
  __syncthreads();
  for (int i = t; i < n; i += 256) {
    int d = dst[c0 + i];
    int s = src[c0 + i];
    int b = d / NPB;
    int ld = d - b * NPB;
    ent[i] = ((unsigned)ld << 17) | (unsigned)s;
    binv[i] = (short)b;
    atomicAdd(&lcnt[b], 1);
  }
  __syncthreads();
  for (int i = t; i < NBIN; i += 256)
    lbase[i] = atomicAdd(&binCur[i], lcnt[i]);
  __syncthreads();
  for (int i = t; i < n; i += 256) {
    int b = binv[i];
    int slot = atomicAdd(&lbase[b], 1);
    if (slot < BCAP) staging[(size_t)b * BCAP + slot] = ent[i];
  }
}

__global__ __launch_bounds__(256) void sort_kernel(const unsigned* __restrict__ staging,
                                                   const int* __restrict__ binCur,
                                                   float* __restrict__ dinv,
                                                   int2* __restrict__ rowSE,
                                                   int* __restrict__ perm,
                                                   int* __restrict__ csr) {
  __shared__ unsigned in[BCAP];
  __shared__ int outw[CSRCAP];
  __shared__ int cnt[NPB];
  __shared__ int hist[64];
  __shared__ int histCur[64];
  __shared__ int rnk[NPB];
  __shared__ int pd[256];
  __shared__ int ptot;
  int b = blockIdx.x, t = threadIdx.x;
  int n = min(binCur[b], BCAP);
  const unsigned* st = staging + (size_t)b * BCAP;
  for (int i = t; i < NPB; i += 256) cnt[i] = 0;
  if (t < 64) hist[t] = 0;
  __syncthreads();
  for (int i = t; i < n; i += 256) {
    unsigned e = st[i];
    in[i] = e;
    atomicAdd(&cnt[e >> 17], 1);
  }
  __syncthreads();
  int deg = (t < NPB) ? cnt[t] : 0;
  int db = min(deg, 63);
  if (t < NPB) atomicAdd(&hist[db], 1);
  __syncthreads();
  if (t < 64) {                       // exclusive scan of 64-bucket degree histogram
    int h = hist[t];
    int x = h;
    #pragma unroll
    for (int off = 1; off < 64; off <<= 1) {
      int y = __shfl_up(x, off);
      if (t >= off) x += y;
    }
    histCur[t] = x - h;
  }
  __syncthreads();
  int rank = 0;
  if (t < NPB) {
    rank = atomicAdd(&histCur[db], 1);  // unique rank, degree-ascending
    rnk[t] = rank;
  }
  pd[t] = 0;
  __syncthreads();
  int pdeg = (deg + 7) & ~7;
  if (t < NPB) pd[rank] = pdeg;
  __syncthreads();
  for (int off = 1; off < 256; off <<= 1) {   // inclusive scan of padded degrees (rank order)
    int a = (t >= off) ? pd[t - off] : 0;
    __syncthreads();
    pd[t] += a;
    __syncthreads();
  }
  if (t == 255) ptot = pd[255];
  __syncthreads();
  int base = b * CSRCAP;
  if (t < NPB) {
    int r = rnk[t];
    int excl = pd[r] - pdeg;
    int v = b * NPB + t;
    int pos = b * NPB + r;
    dinv[v] = rsqrtf((float)deg + 1.0f);
    rowSE[pos] = make_int2(base + excl, base + excl + pdeg);
    perm[pos] = v;
    cnt[t] = excl;                    // scatter cursor (node-local id)
  }
  if (b == 0 && t == 0) dinv[N_NODES] = 0.f;   // sentinel
  __syncthreads();
  int ptotal = min(ptot, CSRCAP);
  for (int i = t; i < ptotal; i += 256) outw[i] = N_NODES;   // sentinel fill
  __syncthreads();
  for (int i = t; i < n; i += 256) {
    unsigned e = in[i];
    int p = atomicAdd(&cnt[e >> 17], 1);
    if (p < CSRCAP) outw[p] = (int)(e & 0x1FFFFu);
  }
  __syncthreads();
  for (int i = t; i < ptotal; i += 256) csr[base + i] = outw[i];
}

// ---------------- GEMM layer 1: fp32 X [N,75] @ W -> bf16 Hs (VALU) ----------------

__global__ __launch_bounds__(256) void gemm1_kernel(
    const float* __restrict__ X, const float* __restrict__ W,
    const float* __restrict__ dinv, unsigned short* __restrict__ Hout) {
  __shared__ float xs[N_FEAT][XPAD];   // [k][row]
  __shared__ float ws[N_FEAT][64];     // [k][col]
  int t = threadIdx.x;
  int rowBase = blockIdx.x * 64;
  for (int i = t; i < N_FEAT * 64; i += 256) ws[i >> 6][i & 63] = W[i];
  if (rowBase + 64 <= N_NODES) {
    const float* Xb = X + (size_t)rowBase * N_FEAT;
    for (int i = t; i < 64 * N_FEAT; i += 256) {
      int r = i / N_FEAT, k = i - r * N_FEAT;
      xs[k][r] = Xb[i];
    }
  } else {
    for (int i = t; i < 64 * N_FEAT; i += 256) {
      int r = i / N_FEAT, k = i - r * N_FEAT;
      int row = rowBase + r;
      xs[k][r] = (row < N_NODES) ? X[(size_t)row * N_FEAT + k] : 0.f;
    }
  }
  __syncthreads();
  int ty = t >> 4, tx = t & 15;
  int r0 = ty * 4, c0 = tx * 4;
  float acc[4][4] = {};
  for (int k = 0; k < N_FEAT; ++k) {
    float4 a = *(const float4*)&xs[k][r0];
    float4 bq = *(const float4*)&ws[k][c0];
    float av[4] = {a.x, a.y, a.z, a.w};
    float bv[4] = {bq.x, bq.y, bq.z, bq.w};
    #pragma unroll
    for (int i = 0; i < 4; ++i)
      #pragma unroll
      for (int j = 0; j < 4; ++j)
        acc[i][j] = fmaf(av[i], bv[j], acc[i][j]);
  }
  #pragma unroll
  for (int i = 0; i < 4; ++i) {
    int row = rowBase + r0 + i;
    if (row < N_NODES) {
      float dv = dinv[row];
      uint2 packed = make_uint2(bf2_pack(acc[i][0] * dv, acc[i][1] * dv),
                                bf2_pack(acc[i][2] * dv, acc[i][3] * dv));
      *(uint2*)&Hout[(size_t)row * HID + c0] = packed;
    } else if (row == N_NODES) {
      *(uint2*)&Hout[(size_t)row * HID + c0] = make_uint2(0u, 0u);
    }
  }
}

// ---------------- layers 1-4 FUSED: gather(Z) -> MFMA(Wsw) -> relu/BN-stats -> Z ------
// Layer 1 uses a swizzled IDENTITY W (MFMA = free transpose of the gather acc) and
// computeS=1: the gather also accumulates sdv = sum dinv[src] and writes
// S[v] = dv*(dv+sdv) (folds the former ssum_kernel into the same csr walk).
// Contiguous heavy-first block mapping (best measured config, R4 = 394.7 us).
// The gather runs at the hardware random-128B-line floor (~2.1 TB/s): invariant
// to occupancy (8->16 waves/CU), per-wave MLP (x4 vs x8), neighbor ordering, and
// wave balance (R1/R2/R3/R5/R6 experiments) — do not re-litigate without new HW insight.

#define FB_POS 64

__global__ __launch_bounds__(256) void fusedB_kernel(
    const unsigned short* __restrict__ Zin, const unsigned short* __restrict__ Wsw,
    const int* __restrict__ csr, const int2* __restrict__ rowSE,
    const int* __restrict__ perm, float* __restrict__ Ssum,
    const float* __restrict__ dinv, const float* __restrict__ cvec,
    const float* __restrict__ bias, unsigned short* __restrict__ Zout,
    float* __restrict__ stats, int scaleOut, int computeS) {
  __shared__ float ldsC[64][68];
  __shared__ float redS[4][64];
  __shared__ float redQ[4][64];
  int t = threadIdx.x;
  int w = t >> 6, lane = t & 63;
  int q = lane >> 4, li = lane & 15;
  int bb = (int)gridDim.x - 1 - (int)blockIdx.x;   // heavy blocks first
  int pos0 = bb * FB_POS;

  if (bb == 0 && t < 8)   // zero sentinel row of the OUTPUT buffer
    ((uint4*)(Zout + (size_t)N_NODES * HID))[t] = make_uint4(0u, 0u, 0u, 0u);

  // ---- gather phase ----
  int pos = pos0 + w * 16 + li;
  float aLo[8] = {0.f, 0.f, 0.f, 0.f, 0.f, 0.f, 0.f, 0.f};
  float aHi[8] = {0.f, 0.f, 0.f, 0.f, 0.f, 0.f, 0.f, 0.f};
  float sdv = 0.f;
  const unsigned short* Zq = Zin + q * 8;
  if (pos < N_NODES) {
    int v = perm[pos];
    int2 se = rowSE[pos];
    const unsigned short* rs = Zq + (size_t)v * HID;
    uint4 sl = *(const uint4*)rs;
    uint4 sh = *(const uint4*)(rs + 32);
    acc8(aLo, sl); acc8(aHi, sh);
    if (computeS) {
      for (int e = se.x; e < se.y; e += 4) {
        int4 cc = *(const int4*)&csr[e];
        const unsigned short* r0 = Zq + (size_t)cc.x * HID;
        const unsigned short* r1 = Zq + (size_t)cc.y * HID;
        const unsigned short* r2 = Zq + (size_t)cc.z * HID;
        const unsigned short* r3 = Zq + (size_t)cc.w * HID;
        uint4 l0 = *(const uint4*)r0, h0 = *(const uint4*)(r0 + 32);
        uint4 l1 = *(const uint4*)r1, h1 = *(const uint4*)(r1 + 32);
        uint4 l2 = *(const uint4*)r2, h2 = *(const uint4*)(r2 + 32);
        uint4 l3 = *(const uint4*)r3, h3 = *(const uint4*)(r3 + 32);
        sdv += (dinv[cc.x] + dinv[cc.y]) + (dinv[cc.z] + dinv[cc.w]);
        acc8(aLo, l0); acc8(aHi, h0);
        acc8(aLo, l1); acc8(aHi, h1);
        acc8(aLo, l2); acc8(aHi, h2);
        acc8(aLo, l3); acc8(aHi, h3);
      }
      if (q == 0) {
        float dvv = dinv[v];
        Ssum[v] = dvv * (dvv + sdv);
      }
    } else {
      for (int e = se.x; e < se.y; e += 4) {
        int4 cc = *(const int4*)&csr[e];
        const unsigned short* r0 = Zq + (size_t)cc.x * HID;
        const unsigned short* r1 = Zq + (size_t)cc.y * HID;
        const unsigned short* r2 = Zq + (size_t)cc.z * HID;
        const unsigned short* r3 = Zq + (size_t)cc.w * HID;
        uint4 l0 = *(const uint4*)r0, h0 = *(const uint4*)(r0 + 32);
        uint4 l1 = *(const uint4*)r1, h1 = *(const uint4*)(r1 + 32);
        uint4 l2 = *(const uint4*)r2, h2 = *(const uint4*)(r2 + 32);
        uint4 l3 = *(const uint4*)r3, h3 = *(const uint4*)(r3 + 32);
        acc8(aLo, l0); acc8(aHi, h0);
        acc8(aLo, l1); acc8(aHi, h1);
        acc8(aLo, l2); acc8(aHi, h2);
        acc8(aLo, l3); acc8(aHi, h3);
      }
    }
  }
  // ---- pack A-frags + MFMA (whole wave, masked rows are zero) ----
  bf16x8 a0, a1;
  #pragma unroll
  for (int j = 0; j < 8; ++j) {
    a0[j] = (short)bf1_pack(aLo[j]);
    a1[j] = (short)bf1_pack(aHi[j]);
  }
  const bf16x8* Wr = (const bf16x8*)Wsw;
  f32x4 accs[4];
  #pragma unroll
  for (int nt = 0; nt < 4; ++nt) {
    bf16x8 b0 = Wr[(nt * 2 + 0) * 64 + lane];
    bf16x8 b1 = Wr[(nt * 2 + 1) * 64 + lane];
    f32x4 acc = {0.f, 0.f, 0.f, 0.f};
    acc = __builtin_amdgcn_mfma_f32_16x16x32_bf16(a0, b0, acc, 0, 0, 0);
    acc = __builtin_amdgcn_mfma_f32_16x16x32_bf16(a1, b1, acc, 0, 0, 0);
    accs[nt] = acc;
  }
  // ---- epilogue: C row = q*4+r, col = nt*16+li ----
  float dv[4], sv[4], st[4];
  #pragma unroll
  for (int r = 0; r < 4; ++r) {
    int pr = pos0 + w * 16 + q * 4 + r;
    if (pr < N_NODES) {
      int vr = perm[pr];
      dv[r] = dinv[vr];
      sv[r] = computeS ? 0.f : Ssum[vr];   // layer 1: cvec==0, S unused
    } else { dv[r] = 0.f; sv[r] = 0.f; }
    st[r] = scaleOut ? dv[r] : 1.f;
  }
  float ss[4] = {0.f, 0.f, 0.f, 0.f}, sq[4] = {0.f, 0.f, 0.f, 0.f};
  #pragma unroll
  for (int nt = 0; nt < 4; ++nt) {
    float cl = cvec[nt * 16 + li];
    float bl = bias[nt * 16 + li];
    #pragma unroll
    for (int r = 0; r < 4; ++r) {
      int pr = pos0 + w * 16 + q * 4 + r;
      float z = fmaxf(fmaf(dv[r], accs[nt][r], fmaf(sv[r], cl, bl)), 0.f);
      if (pr >= N_NODES) z = 0.f;
      ss[nt] += z;
      sq[nt] += z * z;
      ldsC[w * 16 + q * 4 + r][nt * 16 + li] = z * st[r];
    }
  }
  #pragma unroll
  for (int m = 16; m <= 32; m <<= 1) {
    #pragma unroll
    for (int nt = 0; nt < 4; ++nt) {
      ss[nt] += __shfl_xor(ss[nt], m);
      sq[nt] += __shfl_xor(sq[nt], m);
    }
  }
  if (q == 0) {
    #pragma unroll
    for (int nt = 0; nt < 4; ++nt) {
      redS[w][nt * 16 + li] = ss[nt];
      redQ[w][nt * 16 + li] = sq[nt];
    }
  }
  __syncthreads();
  if (w == 0) {
    float s = redS[0][lane] + redS[1][lane] + redS[2][lane] + redS[3][lane];
    float qq = redQ[0][lane] + redQ[1][lane] + redQ[2][lane] + redQ[3][lane];
    float* slp = stats + (size_t)(blockIdx.x & (NSLICE - 1)) * 128;
    atomicAdd(&slp[lane], s);
    atomicAdd(&slp[64 + lane], qq);
  }
  // ---- transpose out via LDS: 4 threads/row, 32B each, contiguous 128B rows ----
  int rl = t >> 2, cq = t & 3;
  int pr2 = pos0 + rl;
  if (pr2 < N_NODES) {
    int v2 = perm[pr2];
    unsigned p[8];
    #pragma unroll
    for (int j = 0; j < 8; ++j)
      p[j] = bf2_pack(ldsC[rl][cq * 16 + 2 * j], ldsC[rl][cq * 16 + 2 * j + 1]);
    uint4* dp = (uint4*)(Zout + (size_t)v2 * HID + cq * 16);
    dp[0] = make_uint4(p[0], p[1], p[2], p[3]);
    dp[1] = make_uint4(p[4], p[5], p[6], p[7]);
  }
}

// ---------------- BN fold: alpha/beta, Wsw = swizzled bf16(alpha⊙W), c = beta@W -------
// Parallelized: 256-thread slice reduction (NSLICE=16, 8 loads/thread) and 4-way
// k-split cvec dot products.

__global__ __launch_bounds__(256) void prep_kernel(
    const float* __restrict__ stats, const float* __restrict__ g,
    const float* __restrict__ be, const float* __restrict__ Wnext,
    unsigned short* __restrict__ Wsw, float* __restrict__ cvec,
    float* __restrict__ ab, int hasNext) {
  __shared__ float tmp2[256];
  __shared__ float alpha[64];
  __shared__ float beta[64];
  __shared__ float cpart[4][64];
  int t = threadIdx.x;
  {
    int elem = t & 127, half = t >> 7;
    float s = 0.f;
    #pragma unroll
    for (int i = 0; i < NSLICE / 2; ++i)
      s += stats[(size_t)(half * (NSLICE / 2) + i) * 128 + elem];
    tmp2[t] = s;
  }
  __syncthreads();
  if (t < 64) {
    float sm = tmp2[t] + tmp2[t + 128];
    float sq = tmp2[64 + t] + tmp2[192 + t];
    float m = sm / (float)N_NODES;
    float var = sq / (float)N_NODES - m * m;
    float a = g[t] * rsqrtf(var + BN_EPS);
    alpha[t] = a;
    float bt = be[t] - m * a;
    beta[t] = bt;
    ab[t] = a;
    ab[64 + t] = bt;
  }
  __syncthreads();
  if (hasNext) {
    for (int idx = t; idx < HID * HID; idx += 256) {
      int j = idx & 7, lane2 = (idx >> 3) & 63, rest = idx >> 9;
      int kc = rest & 1, nt = rest >> 1;
      int k = kc * 32 + ((lane2 >> 4) & 3) * 8 + j;
      int nn = nt * 16 + (lane2 & 15);
      Wsw[idx] = bf1_pack(alpha[k] * Wnext[k * HID + nn]);
    }
    {
      int col = t & 63, kseg = t >> 6;
      float c = 0.f;
      #pragma unroll
      for (int i = 0; i < 16; ++i) {
        int k = kseg * 16 + i;
        c += beta[k] * Wnext[k * HID + col];
      }
      cpart[kseg][col] = c;
    }
    __syncthreads();
    if (t < 64)
      cvec[t] = (cpart[0][t] + cpart[1][t]) + (cpart[2][t] + cpart[3][t]);
  }
}

// ---------------- pool (bf16 Z, unscaled layer-4 output) ----------------

#define POOL_CH 64

__global__ __launch_bounds__(256) void pool_kernel(
    const unsigned short* __restrict__ Z, const int* __restrict__ batch,
    const float* __restrict__ ab, float* __restrict__ out) {
  int tid = blockIdx.x * blockDim.x + threadIdx.x;
  int w = tid >> 6, lane = tid & 63;
  int v0 = w * POOL_CH;
  if (v0 >= N_NODES) return;
  int v1 = min(N_NODES, v0 + POOL_CH);
  float a = ab[lane], b = ab[64 + lane];
  float acc = 0.f;
  int cur = batch[v0];
  for (int v = v0; v < v1; ++v) {
    int bg = batch[v];
    if (bg != cur) {
      atomicAdd(&out[(size_t)cur * HID + lane], acc);
      acc = 0.f;
      cur = bg;
    }
    acc = fmaf(bf1_unpack(Z[(size_t)v * HID + lane]), a, acc + b);
  }
  atomicAdd(&out[(size_t)cur * HID + lane], acc);
}

// ---------------- launch ----------------

extern "C" void kernel_launch(void* const* d_in, const int* in_sizes, int n_in,
                              void* d_out, int out_size, void* d_ws, size_t ws_size,
                              hipStream_t stream) {
  const float* x    = (const float*)d_in[0];
  const int* src    = (const int*)d_in[1];
  const int* dst    = (const int*)d_in[2];
  const int* batch  = (const int*)d_in[3];
  const float* W[4]  = {(const float*)d_in[4], (const float*)d_in[8],
                        (const float*)d_in[12], (const float*)d_in[16]};
  const float* b[4]  = {(const float*)d_in[5], (const float*)d_in[9],
                        (const float*)d_in[13], (const float*)d_in[17]};
  const float* g[4]  = {(const float*)d_in[6], (const float*)d_in[10],
                        (const float*)d_in[14], (const float*)d_in[18]};
  const float* be[4] = {(const float*)d_in[7], (const float*)d_in[11],
                        (const float*)d_in[15], (const float*)d_in[19]};

  char* wsb = (char*)d_ws;
  size_t off = 0;
  auto alloc = [&](size_t bytes) -> void* {
    void* p = wsb + off;
    off += (bytes + 255) & ~(size_t)255;
    return p;
  };
  // zeroed region (one memset)
  int*   binCur = (int*)  alloc((size_t)NBIN * 4);
  float* c0     = (float*)alloc(64 * 4);
  float* stats  = (float*)alloc((size_t)4 * NSLICE * 128 * 4);
  size_t zero_bytes = off;
  // non-zeroed
  float* Ssum   = (float*)alloc((size_t)N_NODES * 4);
  int2*  rowSE  = (int2*) alloc((size_t)N_NODES * 8);
  int*   perm   = (int*)  alloc((size_t)N_NODES * 4);
  float* dinv   = (float*)alloc((size_t)(N_NODES + 1) * 4);
  unsigned* staging = (unsigned*)alloc((size_t)NBIN * BCAP * 4);
  int*   csr    = (int*)  alloc((size_t)NBIN * CSRCAP * 4);
  unsigned short* Hb  = (unsigned short*)alloc((size_t)(N_NODES + 1) * HID * 2);
  unsigned short* Z0  = (unsigned short*)alloc((size_t)(N_NODES + 1) * HID * 2);
  unsigned short* Z1  = (unsigned short*)alloc((size_t)(N_NODES + 1) * HID * 2);
  unsigned short* Wsw = (unsigned short*)alloc((size_t)HID * HID * 2);
  unsigned short* WswId = (unsigned short*)alloc((size_t)HID * HID * 2);
  float* cv     = (float*)alloc(64 * 4);
  float* ab     = (float*)alloc(128 * 4);

  hipMemsetAsync(d_ws, 0, zero_bytes, stream);
  hipMemsetAsync(d_out, 0, (size_t)out_size * 4, stream);

  bin_kernel<<<BIN_BLOCKS, 256, 0, stream>>>(src, dst, binCur, staging, WswId);
  sort_kernel<<<NBIN, 256, 0, stream>>>(staging, binCur, dinv, rowSE, perm, csr);

  int gemmBlocks = (N_NODES + 64) / 64;   // covers sentinel row N_NODES
  int fusedBlocks = (N_NODES + FB_POS - 1) / FB_POS;

  // layer 1 (K=75, c=0): gemm1 -> fused gather with identity W (MFMA = transpose),
  // computeS=1 folds the former ssum_kernel into the gather.
  gemm1_kernel<<<gemmBlocks, 256, 0, stream>>>(x, W[0], dinv, Hb);
  fusedB_kernel<<<fusedBlocks, 256, 0, stream>>>(Hb, WswId, csr, rowSE, perm, Ssum, dinv,
                                                 c0, b[0], Z0, stats, 1, 1);
  prep_kernel<<<1, 256, 0, stream>>>(stats, g[0], be[0], W[1], Wsw, cv, ab, 1);

  // layers 2..4: fused gather+MFMA+BN-stats, ping-pong Z buffers
  fusedB_kernel<<<fusedBlocks, 256, 0, stream>>>(Z0, Wsw, csr, rowSE, perm, Ssum, dinv,
                                                 cv, b[1], Z1, stats + (size_t)1 * NSLICE * 128, 1, 0);
  prep_kernel<<<1, 256, 0, stream>>>(stats + (size_t)1 * NSLICE * 128, g[1], be[1],
                                     W[2], Wsw, cv, ab, 1);
  fusedB_kernel<<<fusedBlocks, 256, 0, stream>>>(Z1, Wsw, csr, rowSE, perm, Ssum, dinv,
                                                 cv, b[2], Z0, stats + (size_t)2 * NSLICE * 128, 1, 0);
  prep_kernel<<<1, 256, 0, stream>>>(stats + (size_t)2 * NSLICE * 128, g[2], be[2],
                                     W[3], Wsw, cv, ab, 1);
  fusedB_kernel<<<fusedBlocks, 256, 0, stream>>>(Z0, Wsw, csr, rowSE, perm, Ssum, dinv,
                                                 cv, b[3], Z1, stats + (size_t)3 * NSLICE * 128, 0, 0);
  prep_kernel<<<1, 256, 0, stream>>>(stats + (size_t)3 * NSLICE * 128, g[3], be[3],
                                     nullptr, Wsw, cv, ab, 0);

  int poolBlocks = (N_NODES + 4 * POOL_CH - 1) / (4 * POOL_CH);
  pool_kernel<<<poolBlocks, 256, 0, stream>>>(Z1, batch, ab, (float*)d_out);
}